// Round 1
// baseline (9412.350 us; speedup 1.0000x reference)
//
#include <hip/hip_runtime.h>
#include <math.h>

#define B_   2
#define T_   2048
#define V_   32000
#define DM   1024
#define DI_  2048
#define NS   16
#define RR   64
#define LL   4
#define KK   4
#define BT   (B_*T_)

__device__ __forceinline__ float siluf(float x){ return x / (1.0f + __expf(-x)); }
__device__ __forceinline__ float softplusf(float x){
    return (x > 20.0f) ? x : log1pf(__expf(x));
}

// ---------------------------------------------------------------- embedding
__global__ __launch_bounds__(256) void embed_kernel(
    const int* __restrict__ ids, const float* __restrict__ W, float* __restrict__ x)
{
    int idx = blockIdx.x * 256 + threadIdx.x;     // over BT*DM
    int d  = idx & (DM - 1);
    int bt = idx >> 10;
    x[idx] = W[(size_t)ids[bt] * DM + d];
}

// ---------------------------------------------------------------- layernorm (row = 1024)
__global__ __launch_bounds__(256) void ln_kernel(
    const float* __restrict__ x, const float* __restrict__ w,
    const float* __restrict__ b, float* __restrict__ o)
{
    int row = blockIdx.x;
    const float4* xr = (const float4*)(x + (size_t)row * DM);
    float4 v = xr[threadIdx.x];
    float s = v.x + v.y + v.z + v.w;
    float q = v.x*v.x + v.y*v.y + v.z*v.z + v.w*v.w;
    #pragma unroll
    for (int off = 32; off > 0; off >>= 1) {
        s += __shfl_down(s, off);
        q += __shfl_down(q, off);
    }
    __shared__ float rs_[4], rq_[4];
    __shared__ float mu_s, inv_s;
    int lane = threadIdx.x & 63, wv = threadIdx.x >> 6;
    if (lane == 0) { rs_[wv] = s; rq_[wv] = q; }
    __syncthreads();
    if (threadIdx.x == 0) {
        float S = rs_[0] + rs_[1] + rs_[2] + rs_[3];
        float Q = rq_[0] + rq_[1] + rq_[2] + rq_[3];
        float mu  = S * (1.0f / DM);
        float var = Q * (1.0f / DM) - mu * mu;
        mu_s = mu; inv_s = rsqrtf(var + 1e-5f);
    }
    __syncthreads();
    float mu = mu_s, inv = inv_s;
    float4 wv4 = ((const float4*)w)[threadIdx.x];
    float4 bv4 = ((const float4*)b)[threadIdx.x];
    float4 r;
    r.x = (v.x - mu) * inv * wv4.x + bv4.x;
    r.y = (v.y - mu) * inv * wv4.y + bv4.y;
    r.z = (v.z - mu) * inv * wv4.z + bv4.z;
    r.w = (v.w - mu) * inv * wv4.w + bv4.w;
    ((float4*)(o + (size_t)row * DM))[threadIdx.x] = r;
}

// ---------------------------------------------------------------- causal dwconv(K=4) + silu
__global__ __launch_bounds__(256) void conv_silu_kernel(
    const float* __restrict__ xz, const float* __restrict__ cw,
    const float* __restrict__ cb, float* __restrict__ xc)
{
    int idx = blockIdx.x * 256 + threadIdx.x;     // over BT*DI_
    int c  = idx & (DI_ - 1);
    int bt = idx >> 11;
    int t  = bt & (T_ - 1);
    const float* base = xz + (size_t)bt * (2 * DI_) + c;
    float w0 = cw[c*KK+0], w1 = cw[c*KK+1], w2 = cw[c*KK+2], w3 = cw[c*KK+3];
    float acc = cb[c];
    if (t >= 3) acc += base[-3 * 2 * DI_] * w0;
    if (t >= 2) acc += base[-2 * 2 * DI_] * w1;
    if (t >= 1) acc += base[-1 * 2 * DI_] * w2;
    acc += base[0] * w3;
    xc[idx] = siluf(acc);
}

// ---------------------------------------------------------------- selective scan
// block = 256 threads = 16 channels x 16 states; grid = B * DI/16
// y (in-place over xc) = (scan_out + u*D) * silu(z)
__global__ __launch_bounds__(256) void scan_kernel(
    const float* __restrict__ dt, int dt_stride,
    const float* __restrict__ u,
    const float* __restrict__ proj,
    const float* __restrict__ z, int z_stride,
    const float* __restrict__ A_log, const float* __restrict__ Dp,
    float* __restrict__ y)
{
    int b   = blockIdx.x / (DI_ / 16);
    int di0 = (blockIdx.x % (DI_ / 16)) * 16;
    int tid = threadIdx.x;
    int ci = tid >> 4, n = tid & 15;
    int di = di0 + ci;
    float Av = -__expf(A_log[di * NS + n]);
    float Dv = Dp[di];

    __shared__ float dt_s[16][16], u_s[16][16], Bs[16][16], Cs[16][16], ys[16][16];

    int li = tid >> 4;     // t-offset for cooperative load
    int lc = tid & 15;     // channel / state col for cooperative load

    float h = 0.0f;
    for (int t0 = 0; t0 < T_; t0 += 16) {
        size_t bt = (size_t)b * T_ + t0 + li;
        dt_s[li][lc] = dt[bt * dt_stride + di0 + lc];
        u_s[li][lc]  = u[bt * DI_ + di0 + lc];
        Bs[li][lc]   = proj[bt * (RR + 2*NS) + RR + lc];
        Cs[li][lc]   = proj[bt * (RR + 2*NS) + RR + NS + lc];
        __syncthreads();
        #pragma unroll
        for (int i = 0; i < 16; i++) {
            float dtv = dt_s[i][ci];
            float uv  = u_s[i][ci];
            float dA  = __expf(dtv * Av);
            h = dA * h + dtv * uv * Bs[i][n];
            float p = h * Cs[i][n];
            p += __shfl_xor(p, 1, 16);
            p += __shfl_xor(p, 2, 16);
            p += __shfl_xor(p, 4, 16);
            p += __shfl_xor(p, 8, 16);
            if (n == 0) ys[i][ci] = p + uv * Dv;
        }
        __syncthreads();
        float yv = ys[li][lc];
        float zv = z[bt * z_stride + di0 + lc];
        y[bt * DI_ + di0 + lc] = yv * siluf(zv);
        // no extra sync needed: next load writes dt_s/u_s/Bs/Cs (read only before
        // sync #2), next ys write happens after next chunk's first sync.
    }
}

// ---------------------------------------------------------------- fp32 NT GEMM
// C[m,n] = sum_k A[m,k]*B[n,k]  (+bias[n]) (softplus) (+Res[m,n])
// 64x64 tile, BK=16, 256 threads, 4x4 acc per thread.
// EPI bits: 1=bias, 2=softplus, 4=residual
template<int EPI>
__global__ __launch_bounds__(256) void gemm_nt(
    const float* __restrict__ A, int lda,
    const float* __restrict__ Bm, int ldb,
    float* __restrict__ C, int ldc,
    const float* __restrict__ bias,
    const float* __restrict__ Res, int ldres,
    int N, int Kd)
{
    __shared__ __align__(16) float As[16 * 68];
    __shared__ __align__(16) float Bs[16 * 68];
    int tid = threadIdx.x;
    int n0 = blockIdx.x * 64, m0 = blockIdx.y * 64;
    int row = tid >> 2, kq = tid & 3;          // loader mapping
    int tx = tid & 15, ty = tid >> 4;          // compute mapping
    float acc[4][4] = {};

    const float* Aptr = A + (size_t)(m0 + row) * lda + kq * 4;
    const float* Bptr = Bm + (size_t)(n0 + row) * ldb + kq * 4;
    bool bvalid = (n0 + row) < N;

    for (int k0 = 0; k0 < Kd; k0 += 16) {
        float4 av = *(const float4*)(Aptr + k0);
        float4 bv = bvalid ? *(const float4*)(Bptr + k0) : make_float4(0.f,0.f,0.f,0.f);
        __syncthreads();
        As[(kq*4+0)*68 + row] = av.x;
        As[(kq*4+1)*68 + row] = av.y;
        As[(kq*4+2)*68 + row] = av.z;
        As[(kq*4+3)*68 + row] = av.w;
        Bs[(kq*4+0)*68 + row] = bv.x;
        Bs[(kq*4+1)*68 + row] = bv.y;
        Bs[(kq*4+2)*68 + row] = bv.z;
        Bs[(kq*4+3)*68 + row] = bv.w;
        __syncthreads();
        const float4* A4 = (const float4*)As;
        const float4* B4 = (const float4*)Bs;
        #pragma unroll
        for (int k = 0; k < 16; k++) {
            float4 a = A4[k*17 + ty];
            float4 b = B4[k*17 + tx];
            acc[0][0] += a.x*b.x; acc[0][1] += a.x*b.y; acc[0][2] += a.x*b.z; acc[0][3] += a.x*b.w;
            acc[1][0] += a.y*b.x; acc[1][1] += a.y*b.y; acc[1][2] += a.y*b.z; acc[1][3] += a.y*b.w;
            acc[2][0] += a.z*b.x; acc[2][1] += a.z*b.y; acc[2][2] += a.z*b.z; acc[2][3] += a.z*b.w;
            acc[3][0] += a.w*b.x; acc[3][1] += a.w*b.y; acc[3][2] += a.w*b.z; acc[3][3] += a.w*b.w;
        }
    }
    #pragma unroll
    for (int i = 0; i < 4; i++) {
        int m = m0 + ty*4 + i;
        #pragma unroll
        for (int j = 0; j < 4; j++) {
            int n = n0 + tx*4 + j;
            if (n < N) {
                float v = acc[i][j];
                if (EPI & 1) v += bias[n];
                if (EPI & 2) v = softplusf(v);
                if (EPI & 4) v += Res[(size_t)m * ldres + n];
                C[(size_t)m * ldc + n] = v;
            }
        }
    }
}

// ---------------------------------------------------------------- launch
extern "C" void kernel_launch(void* const* d_in, const int* in_sizes, int n_in,
                              void* d_out, int out_size, void* d_ws, size_t ws_size,
                              hipStream_t stream)
{
    const int*   ids    = (const int*)  d_in[0];
    const float* embedW = (const float*)d_in[1];
    const float* out_b  = (const float*)d_in[2];
    const float* ln_w   = (const float*)d_in[3];
    const float* ln_b   = (const float*)d_in[4];
    const float* norm_w = (const float*)d_in[5];
    const float* norm_b = (const float*)d_in[6];
    const float* inW    = (const float*)d_in[7];   // (L, 2DI, Dm)
    const float* convW  = (const float*)d_in[8];   // (L, DI, K)
    const float* convB  = (const float*)d_in[9];   // (L, DI)
    const float* xW     = (const float*)d_in[10];  // (L, 96, DI)
    const float* dtW    = (const float*)d_in[11];  // (L, DI, R)
    const float* dtB    = (const float*)d_in[12];  // (L, DI)
    const float* Alog   = (const float*)d_in[13];  // (L, DI, N)
    const float* Dp     = (const float*)d_in[14];  // (L, DI)
    const float* oW     = (const float*)d_in[15];  // (L, Dm, DI)

    float* x    = (float*)d_ws;                        // (BT, Dm)    16 MB
    float* h    = x    + (size_t)BT * DM;              // (BT, Dm)    16 MB
    float* xz   = h    + (size_t)BT * DM;              // (BT, 2*DI)  64 MB
    float* xc   = xz   + (size_t)BT * 2 * DI_;         // (BT, DI)    32 MB
    float* proj = xc   + (size_t)BT * DI_;             // (BT, 96)   1.5 MB
    // dt aliases the (dead after conv) x_in half of xz, stride 2*DI_
    float* logits = (float*)d_out;

    embed_kernel<<<BT*DM/256, 256, 0, stream>>>(ids, embedW, x);

    for (int l = 0; l < LL; l++) {
        // h = LN(x)
        ln_kernel<<<BT, 256, 0, stream>>>(x, norm_w + (size_t)l*DM, norm_b + (size_t)l*DM, h);
        // xz = h @ inW^T   (M=4096, N=4096, K=1024)
        gemm_nt<0><<<dim3(64, 64), 256, 0, stream>>>(
            h, DM, inW + (size_t)l*2*DI_*DM, DM, xz, 2*DI_,
            nullptr, nullptr, 0, 2*DI_, DM);
        // xc = silu(conv(x_in) + cb)
        conv_silu_kernel<<<BT*DI_/256, 256, 0, stream>>>(
            xz, convW + (size_t)l*DI_*KK, convB + (size_t)l*DI_, xc);
        // proj = xc @ xW^T  (M=4096, N=96, K=2048)
        gemm_nt<0><<<dim3(2, 64), 256, 0, stream>>>(
            xc, DI_, xW + (size_t)l*(RR+2*NS)*DI_, DI_, proj, RR+2*NS,
            nullptr, nullptr, 0, RR+2*NS, DI_);
        // dt = softplus(proj[:, :R] @ dtW^T + dtB)  -> written into x_in slots of xz
        gemm_nt<3><<<dim3(32, 64), 256, 0, stream>>>(
            proj, RR+2*NS, dtW + (size_t)l*DI_*RR, RR, xz, 2*DI_,
            dtB + (size_t)l*DI_, nullptr, 0, DI_, RR);
        // selective scan: y (in-place over xc) = (scan + u*D) * silu(z)
        scan_kernel<<<B_*(DI_/16), 256, 0, stream>>>(
            xz, 2*DI_, xc, proj, xz + DI_, 2*DI_,
            Alog + (size_t)l*DI_*NS, Dp + (size_t)l*DI_, xc);
        // x = x + y @ oW^T  (M=4096, N=1024, K=2048)
        gemm_nt<4><<<dim3(16, 64), 256, 0, stream>>>(
            xc, DI_, oW + (size_t)l*DM*DI_, DI_, x, DM,
            nullptr, x, DM, DM, DI_);
    }

    // final LN + logits
    ln_kernel<<<BT, 256, 0, stream>>>(x, ln_w, ln_b, h);
    // logits = h @ embedW^T + out_b  (M=4096, N=32000, K=1024)
    gemm_nt<1><<<dim3(V_/64, 64), 256, 0, stream>>>(
        h, DM, embedW, DM, logits, V_,
        out_b, nullptr, 0, V_, DM);
}